// Round 1
// baseline (1466.401 us; speedup 1.0000x reference)
//
#include <hip/hip_runtime.h>
#include <math.h>

#define N_NODES 5000
#define DEG     16
#define S       17
#define T       10
#define MN      10
#define D       128
#define N_OUTER 3
#define N_SINK  5
#define EPS_INV 10.0f   // 1/EPS, EPS = 0.1

// Block layout: 272 threads = 17 rows (s) x 16 lanes (m), m<10 active.
// One block handles one (node n, template t) pair.
__global__ __launch_bounds__(272) void ltfgw_main(
    const float* __restrict__ x,        // [N, D]
    const int*   __restrict__ edge,     // [2, N*DEG]; dst = second row
    const float* __restrict__ tmpl,     // [T, MN, MN]
    const float* __restrict__ F2,       // [T, MN, D]
    const float* __restrict__ q0,       // [T, MN]
    const float* __restrict__ alpha0,   // [1]
    float*       __restrict__ out)      // [N, T]
{
    const int blk = blockIdx.x;
    const int n   = blk / T;
    const int t   = blk % T;
    const int tid = threadIdx.x;
    const int s   = tid >> 4;          // 0..16
    const int m   = tid & 15;          // 0..15
    const bool act = (m < MN);
    const int mc  = act ? m : (MN - 1); // clamped column for safe indexing

    __shared__ int   local_[S];
    __shared__ int   neigh[S][DEG];
    __shared__ float xl[S][D + 4];      // +4 pad -> conflict-free float4 reads
    __shared__ float C1[S][S];
    __shared__ float G[S][16];
    __shared__ float Hm[S][16];
    __shared__ float red[S][16];
    __shared__ float bvec[16];
    __shared__ float C2s[MN][MN];       // C2s[l][k] = C2[t,l,k]
    __shared__ float qs[MN], logqs[MN], hC2s[MN], sqF2s[MN];
    __shared__ float xsq[S], hC1[S];

    const int* dst = edge + N_NODES * DEG;

    // ---- phase A: 1-hop neighborhood node list ----
    if (tid < S) local_[tid] = (tid == 0) ? n : dst[n * DEG + tid - 1];
    __syncthreads();

    // ---- phase B: neighbor lists, local features, template-side prep ----
    // neigh[a][k]: tid covers exactly 17*16
    neigh[s][m] = dst[local_[s] * DEG + m];
    {   // xl[s][0..127]: each thread loads 8 floats
        const float4* xr = (const float4*)(x + (size_t)local_[s] * D);
        float4 v0 = xr[m * 2 + 0];
        float4 v1 = xr[m * 2 + 1];
        *((float4*)&xl[s][m * 8])     = v0;
        *((float4*)&xl[s][m * 8 + 4]) = v1;
    }
    if (tid >= 64 && tid < 64 + MN) {   // C2 = softmax(templates, axis=1): column j
        int j = tid - 64;
        float v[MN]; float mx = -3.4e38f;
        for (int i = 0; i < MN; ++i) { v[i] = tmpl[t * MN * MN + i * MN + j]; mx = fmaxf(mx, v[i]); }
        float sm = 0.f;
        for (int i = 0; i < MN; ++i) { v[i] = __expf(v[i] - mx); sm += v[i]; }
        float inv = 1.f / sm;
        for (int i = 0; i < MN; ++i) C2s[i][j] = v[i] * inv;
    }
    if (tid == 96) {                    // q = softmax(q0[t]), log_q
        float v[MN]; float mx = -3.4e38f;
        for (int k = 0; k < MN; ++k) { v[k] = q0[t * MN + k]; mx = fmaxf(mx, v[k]); }
        float sm = 0.f;
        for (int k = 0; k < MN; ++k) sm += __expf(v[k] - mx);
        float lse = mx + __logf(sm);
        for (int k = 0; k < MN; ++k) { qs[k] = __expf(v[k] - lse); logqs[k] = v[k] - lse; }
    }
    if (tid >= 128 && tid < 128 + MN) { // ||F2[t,m]||^2
        int k = tid - 128;
        const float4* fr = (const float4*)(F2 + ((size_t)t * MN + k) * D);
        float acc = 0.f;
        for (int d4 = 0; d4 < D / 4; ++d4) {
            float4 f = fr[d4];
            acc += f.x * f.x + f.y * f.y + f.z * f.z + f.w * f.w;
        }
        sqF2s[k] = acc;
    }
    __syncthreads();

    // ---- phase C: local adjacency C1, hC2, G init ----
    for (int e = tid; e < S * S; e += 272) {
        int a = e / S, b = e % S;
        int la = local_[a], lb = local_[b];
        bool adj = false;
        #pragma unroll
        for (int k = 0; k < DEG; ++k)
            adj = adj || (neigh[a][k] == lb) || (neigh[b][k] == la);
        C1[a][b] = (a != b && adj) ? 1.f : 0.f;
    }
    if (tid >= 32 && tid < 32 + MN) {   // hC2[t,i] = sum_j C2[t,i,j]^2 q[t,j]
        int i = tid - 32;
        float h = 0.f;
        for (int j = 0; j < MN; ++j) { float c = C2s[i][j]; h += c * c * qs[j]; }
        hC2s[i] = h;
    }
    G[s][m] = (1.f / S) * qs[mc];       // G0 = p q^T
    __syncthreads();

    // ---- phase D: hC1, xsq, feature cost M ----
    if (m == 0) {
        float acc = 0.f;
        for (int j = 0; j < S; ++j) acc += C1[s][j];
        hC1[s] = acc * (1.f / S);
        float xs = 0.f;
        for (int d = 0; d < D; ++d) { float v = xl[s][d]; xs += v * v; }
        xsq[s] = xs;
    }
    float dot = 0.f;
    {
        const float4* f2r = (const float4*)(F2 + ((size_t)t * MN + mc) * D);
        const float4* xlr = (const float4*)&xl[s][0];
        #pragma unroll 8
        for (int d4 = 0; d4 < D / 4; ++d4) {
            float4 a4 = xlr[d4];
            float4 b4 = f2r[d4];
            dot += a4.x * b4.x + a4.y * b4.y + a4.z * b4.z + a4.w * b4.w;
        }
    }
    __syncthreads();

    const float Msm    = xsq[s] + sqF2s[mc] - 2.f * dot;
    const float constC = hC1[s] + hC2s[mc];
    const float alpha  = 1.f / (1.f + __expf(-alpha0[0]));
    const float log_p  = -__logf((float)S);

    float aa = 0.f, lk = 0.f;
    for (int o = 0; o < N_OUTER; ++o) {
        // H[j][l] = sum_k G[j][k] * C2[l][k]   (thread (j=s, l=m))
        float h = 0.f;
        #pragma unroll
        for (int k = 0; k < MN; ++k) h += G[s][k] * C2s[mc][k];
        Hm[s][m] = h;
        if (tid < 16) bvec[tid] = 0.f;
        __syncthreads();
        // tens = constC - 2 * sum_j C1[s][j] * H[j][m]
        float acc = 0.f;
        #pragma unroll
        for (int j = 0; j < S; ++j) acc += C1[s][j] * Hm[j][mc];
        float tens = constC - 2.f * acc;
        float cost = (1.f - alpha) * Msm + 2.f * alpha * tens;
        lk = -EPS_INV * cost;

        for (int it = 0; it < N_SINK; ++it) {
            // a-update: logsumexp over m (shuffle within 16-lane row group)
            float z = act ? (lk + bvec[m]) : -3.4e38f;
            float mx = z;
            mx = fmaxf(mx, __shfl_xor(mx, 1, 16));
            mx = fmaxf(mx, __shfl_xor(mx, 2, 16));
            mx = fmaxf(mx, __shfl_xor(mx, 4, 16));
            mx = fmaxf(mx, __shfl_xor(mx, 8, 16));
            float e = __expf(z - mx);     // sentinel -> exp(-inf) = 0
            float sm = e;
            sm += __shfl_xor(sm, 1, 16);
            sm += __shfl_xor(sm, 2, 16);
            sm += __shfl_xor(sm, 4, 16);
            sm += __shfl_xor(sm, 8, 16);
            aa = log_p - (mx + __logf(sm));
            // b-update: logsumexp over s (LDS, 10 reducer threads)
            red[s][m] = lk + aa;
            __syncthreads();
            if (tid < MN) {
                float v[S]; float mx2 = -3.4e38f;
                #pragma unroll
                for (int ss = 0; ss < S; ++ss) { v[ss] = red[ss][tid]; mx2 = fmaxf(mx2, v[ss]); }
                float s2 = 0.f;
                #pragma unroll
                for (int ss = 0; ss < S; ++ss) s2 += __expf(v[ss] - mx2);
                bvec[tid] = logqs[tid] - (mx2 + __logf(s2));
            }
            __syncthreads();
        }
        G[s][m] = __expf(lk + aa + bvec[mc]);
        __syncthreads();
    }

    // ---- final: tens with final G, dist = sum G * ((1-a)M + a*tens) ----
    float h = 0.f;
    #pragma unroll
    for (int k = 0; k < MN; ++k) h += G[s][k] * C2s[mc][k];
    Hm[s][m] = h;
    __syncthreads();
    float acc = 0.f;
    #pragma unroll
    for (int j = 0; j < S; ++j) acc += C1[s][j] * Hm[j][mc];
    float tens = constC - 2.f * acc;
    float val = act ? (G[s][m] * ((1.f - alpha) * Msm + alpha * tens)) : 0.f;
    val += __shfl_xor(val, 1, 16);
    val += __shfl_xor(val, 2, 16);
    val += __shfl_xor(val, 4, 16);
    val += __shfl_xor(val, 8, 16);
    if (m == 0) red[s][0] = val;
    __syncthreads();
    if (tid == 0) {
        float tot = 0.f;
        for (int ss = 0; ss < S; ++ss) tot += red[ss][0];
        out[n * T + t] = tot;
    }
}

extern "C" void kernel_launch(void* const* d_in, const int* in_sizes, int n_in,
                              void* d_out, int out_size, void* d_ws, size_t ws_size,
                              hipStream_t stream) {
    const float* x      = (const float*)d_in[0];
    const int*   edge   = (const int*)  d_in[1];
    const float* tmpl   = (const float*)d_in[2];
    const float* F2     = (const float*)d_in[3];
    const float* q0     = (const float*)d_in[4];
    const float* alpha0 = (const float*)d_in[5];
    float*       out    = (float*)d_out;

    hipLaunchKernelGGL(ltfgw_main, dim3(N_NODES * T), dim3(272), 0, stream,
                       x, edge, tmpl, F2, q0, alpha0, out);
}

// Round 2
// 1424.836 us; speedup vs baseline: 1.0292x; 1.0292x over previous
//
#include <hip/hip_runtime.h>
#include <math.h>

#define NN   5000
#define DEG  16
#define S    17
#define T    10
#define MN   10
#define D    128
#define NOUT 3
#define NSK  5

#define WPB   5            // waves per block = templates per block
#define BLOCK (WPB * 64)
#define NEG   -3.0e38f

// One wave handles one (node, template) OT problem entirely in registers +
// shuffles. Lane = q*16 + m (q=0..3, m=0..15, m<10 active). Lane owns rows
// s = q+4r for r=0..3 and row 16 (replicated identically across quads,
// counted once via q==0 masking). Block = 5 waves = 5 templates of one node;
// grid = 2 blocks per node. Only 4 __syncthreads per block (setup only).
__global__ __launch_bounds__(BLOCK, 8) void ltfgw_wave(
    const float* __restrict__ x,        // [N, D]
    const int*   __restrict__ edge,     // [2, N*DEG]
    const float* __restrict__ tmpl,     // [T, MN, MN]
    const float* __restrict__ F2,      // [T, MN, D]
    const float* __restrict__ q0,       // [T, MN]
    const float* __restrict__ alpha0,   // [1]
    float*       __restrict__ out)      // [N, T]
{
    const int n    = blockIdx.x >> 1;
    const int t    = (blockIdx.x & 1) * WPB + (threadIdx.x >> 6);
    const int tid  = threadIdx.x;
    const int w    = tid >> 6;
    const int lane = tid & 63;
    const int q    = lane >> 4;
    const int m    = lane & 15;
    const bool act = (m < MN);
    const int mc   = act ? m : (MN - 1);

    __shared__ int   loc[S];
    __shared__ int   neigh[S][DEG];
    __shared__ float C1s[S][18];              // stride 18: conflict-free row reads
    __shared__ float xsqp[S][8];
    __shared__ float xsqs[S];
    __shared__ float hC1s[S];
    __shared__ float C2l[WPB][MN][17];        // stride 17: conflict-free row reads

    const int* dst = edge + NN * DEG;

    // ---- setup barrier 1: local node list ----
    if (tid < S) loc[tid] = (tid == 0) ? n : dst[n * DEG + tid - 1];
    __syncthreads();

    // ---- neighbor lists + xsq partials (+ per-wave template prep) ----
    if (tid < S * DEG) neigh[tid >> 4][tid & 15] = dst[loc[tid >> 4] * DEG + (tid & 15)];
    if (tid < S * 8) {
        int s0 = tid >> 3, c = tid & 7;
        const float4* xr = (const float4*)(x + (size_t)loc[s0] * D) + c * 4;
        float acc = 0.f;
        #pragma unroll
        for (int i = 0; i < 4; ++i) { float4 v = xr[i]; acc += v.x*v.x + v.y*v.y + v.z*v.z + v.w*v.w; }
        xsqp[s0][c] = acc;
    }
    // q-softmax LSE (per wave, in registers via width-16 shuffles)
    float vq = q0[t * MN + mc];
    float zq = act ? vq : NEG;
    float mq = zq;
    mq = fmaxf(mq, __shfl_xor(mq, 1, 16));
    mq = fmaxf(mq, __shfl_xor(mq, 2, 16));
    mq = fmaxf(mq, __shfl_xor(mq, 4, 16));
    mq = fmaxf(mq, __shfl_xor(mq, 8, 16));
    float sqv = __expf(zq - mq);
    sqv += __shfl_xor(sqv, 1, 16);
    sqv += __shfl_xor(sqv, 2, 16);
    sqv += __shfl_xor(sqv, 4, 16);
    sqv += __shfl_xor(sqv, 8, 16);
    const float lseq = mq + __logf(sqv);
    const float logq = vq - lseq;            // valid for act lanes
    // C2 = softmax(tmpl, axis=1): active lane m of quad 0 does column m
    if (act && q == 0) {
        float v[MN]; float cm = NEG;
        #pragma unroll
        for (int i = 0; i < MN; ++i) { v[i] = tmpl[t * MN * MN + i * MN + m]; cm = fmaxf(cm, v[i]); }
        float ssum = 0.f;
        #pragma unroll
        for (int i = 0; i < MN; ++i) { v[i] = __expf(v[i] - cm); ssum += v[i]; }
        float inv = 1.f / ssum;
        #pragma unroll
        for (int i = 0; i < MN; ++i) C2l[w][i][m] = v[i] * inv;
    }
    __syncthreads();

    // ---- barrier 3: adjacency C1 (needs neigh), xsq reduce ----
    if (tid < S * S) {
        int a = tid / S, b = tid % S;
        int la = loc[a], lb = loc[b];
        bool adj = false;
        #pragma unroll
        for (int k = 0; k < DEG; ++k) adj = adj | (neigh[a][k] == lb) | (neigh[b][k] == la);
        C1s[a][b] = (a != b && adj) ? 1.f : 0.f;
    }
    if (tid < S) {
        float acc = 0.f;
        #pragma unroll
        for (int c = 0; c < 8; ++c) acc += xsqp[tid][c];
        xsqs[tid] = acc;
    }
    __syncthreads();
    if (tid < S) {
        float acc = 0.f;
        #pragma unroll
        for (int j = 0; j < S; ++j) acc += C1s[tid][j];
        hC1s[tid] = acc * (1.f / S);
    }
    __syncthreads();

    // ================= per-wave main (no more barriers) =================
    float C2row[MN];
    #pragma unroll
    for (int k = 0; k < MN; ++k) C2row[k] = C2l[w][mc][k];

    float hC2 = 0.f;
    #pragma unroll
    for (int j = 0; j < MN; ++j) {
        float qj = __expf(q0[t * MN + j] - lseq);
        hC2 += C2row[j] * C2row[j] * qj;
    }

    const float alpha  = 1.f / (1.f + __expf(-alpha0[0]));
    const float oma    = 1.f - alpha;
    const float log_p  = -__logf((float)S);
    const float qm     = __expf(logq);

    int sr[5];
    #pragma unroll
    for (int r = 0; r < 5; ++r) { int s0 = q + 4 * r; sr[r] = (s0 > 16) ? 16 : s0; }

    // M dots: x rows from global (L1-resident: 17 rows shared by whole block)
    float dot[5] = {0,0,0,0,0};
    float sqf2 = 0.f;
    {
        const float4* f2p = (const float4*)(F2 + ((size_t)t * MN + mc) * D);
        const float4* xp0 = (const float4*)(x + (size_t)loc[sr[0]] * D);
        const float4* xp1 = (const float4*)(x + (size_t)loc[sr[1]] * D);
        const float4* xp2 = (const float4*)(x + (size_t)loc[sr[2]] * D);
        const float4* xp3 = (const float4*)(x + (size_t)loc[sr[3]] * D);
        const float4* xp4 = (const float4*)(x + (size_t)loc[sr[4]] * D);
        #pragma unroll 4
        for (int d4 = 0; d4 < D / 4; ++d4) {
            float4 f = f2p[d4];
            sqf2 += f.x*f.x + f.y*f.y + f.z*f.z + f.w*f.w;
            float4 v;
            v = xp0[d4]; dot[0] += f.x*v.x + f.y*v.y + f.z*v.z + f.w*v.w;
            v = xp1[d4]; dot[1] += f.x*v.x + f.y*v.y + f.z*v.z + f.w*v.w;
            v = xp2[d4]; dot[2] += f.x*v.x + f.y*v.y + f.z*v.z + f.w*v.w;
            v = xp3[d4]; dot[3] += f.x*v.x + f.y*v.y + f.z*v.z + f.w*v.w;
            v = xp4[d4]; dot[4] += f.x*v.x + f.y*v.y + f.z*v.z + f.w*v.w;
        }
    }
    float M_[5], cC[5];
    #pragma unroll
    for (int r = 0; r < 5; ++r) {
        M_[r] = xsqs[sr[r]] + sqf2 - 2.f * dot[r];
        cC[r] = hC1s[sr[r]] + hC2;
    }

    float G[5];
    #pragma unroll
    for (int r = 0; r < 5; ++r) G[r] = qm * (1.f / S);   // G0 = p q^T
    float lk[5], a_[5], b_ = 0.f, tens[5];

    for (int o = 0; o <= NOUT; ++o) {
        // H[j][m] = sum_k G[j][k] * C2[m][k]; lane holds rows of its quad
        float H[5];
        #pragma unroll
        for (int r = 0; r < 5; ++r) {
            float h = 0.f;
            #pragma unroll
            for (int k = 0; k < MN; ++k) h += __shfl(G[r], k, 16) * C2row[k];
            H[r] = h;
        }
        // tens[s][m] = sum_j C1[s][j] * H[j][m]; gather H[j][m] cross-quad
        #pragma unroll
        for (int r = 0; r < 5; ++r) tens[r] = 0.f;
        #pragma unroll
        for (int j = 0; j < 16; ++j) {
            float hj = __shfl(H[j >> 2], ((j & 3) << 4) + m, 64);
            #pragma unroll
            for (int r = 0; r < 5; ++r) tens[r] += C1s[sr[r]][j] * hj;
        }
        {   // j = 16: replicated locally in every quad
            float hj = H[4];
            #pragma unroll
            for (int r = 0; r < 5; ++r) tens[r] += C1s[sr[r]][16] * hj;
        }
        if (o == NOUT) break;   // final tens computed with final G

        #pragma unroll
        for (int r = 0; r < 5; ++r) {
            float cost = oma * M_[r] + 2.f * alpha * (cC[r] - 2.f * tens[r]);
            lk[r] = -10.f * cost;              // logK = -cost/EPS, EPS=0.1
        }
        b_ = 0.f;
        for (int it = 0; it < NSK; ++it) {
            // a-update: a_s = log_p - LSE_m(lk + b)
            float z[5], mx[5], sm[5];
            #pragma unroll
            for (int r = 0; r < 5; ++r) { z[r] = act ? (lk[r] + b_) : NEG; mx[r] = z[r]; }
            #pragma unroll
            for (int r = 0; r < 5; ++r) mx[r] = fmaxf(mx[r], __shfl_xor(mx[r], 1, 16));
            #pragma unroll
            for (int r = 0; r < 5; ++r) mx[r] = fmaxf(mx[r], __shfl_xor(mx[r], 2, 16));
            #pragma unroll
            for (int r = 0; r < 5; ++r) mx[r] = fmaxf(mx[r], __shfl_xor(mx[r], 4, 16));
            #pragma unroll
            for (int r = 0; r < 5; ++r) mx[r] = fmaxf(mx[r], __shfl_xor(mx[r], 8, 16));
            #pragma unroll
            for (int r = 0; r < 5; ++r) sm[r] = __expf(z[r] - mx[r]);
            #pragma unroll
            for (int r = 0; r < 5; ++r) sm[r] += __shfl_xor(sm[r], 1, 16);
            #pragma unroll
            for (int r = 0; r < 5; ++r) sm[r] += __shfl_xor(sm[r], 2, 16);
            #pragma unroll
            for (int r = 0; r < 5; ++r) sm[r] += __shfl_xor(sm[r], 4, 16);
            #pragma unroll
            for (int r = 0; r < 5; ++r) sm[r] += __shfl_xor(sm[r], 8, 16);
            #pragma unroll
            for (int r = 0; r < 5; ++r) a_[r] = log_p - mx[r] - __logf(sm[r]);
            // b-update: b_m = logq - LSE_s(lk + a)
            float w0 = lk[0] + a_[0], w1 = lk[1] + a_[1], w2 = lk[2] + a_[2];
            float w3 = lk[3] + a_[3];
            float w4 = (q == 0) ? (lk[4] + a_[4]) : NEG;  // row 16 counted once
            float mb = fmaxf(fmaxf(fmaxf(w0, w1), fmaxf(w2, w3)), w4);
            mb = fmaxf(mb, __shfl_xor(mb, 16, 64));
            mb = fmaxf(mb, __shfl_xor(mb, 32, 64));
            float sb = __expf(w0 - mb) + __expf(w1 - mb) + __expf(w2 - mb)
                     + __expf(w3 - mb) + __expf(w4 - mb);
            sb += __shfl_xor(sb, 16, 64);
            sb += __shfl_xor(sb, 32, 64);
            b_ = logq - mb - __logf(sb);
        }
        #pragma unroll
        for (int r = 0; r < 5; ++r) G[r] = __expf(lk[r] + a_[r] + b_);
    }

    // dist = sum_{s,m} G * ((1-a) M + a tens)
    float val = 0.f;
    #pragma unroll
    for (int r = 0; r < 5; ++r) {
        float te = cC[r] - 2.f * tens[r];
        float v  = G[r] * (oma * M_[r] + alpha * te);
        bool valid = act && (r < 4 || q == 0);
        val += valid ? v : 0.f;
    }
    val += __shfl_xor(val, 1, 64);
    val += __shfl_xor(val, 2, 64);
    val += __shfl_xor(val, 4, 64);
    val += __shfl_xor(val, 8, 64);
    val += __shfl_xor(val, 16, 64);
    val += __shfl_xor(val, 32, 64);
    if (lane == 0) out[n * T + t] = val;
}

extern "C" void kernel_launch(void* const* d_in, const int* in_sizes, int n_in,
                              void* d_out, int out_size, void* d_ws, size_t ws_size,
                              hipStream_t stream) {
    const float* x      = (const float*)d_in[0];
    const int*   edge   = (const int*)  d_in[1];
    const float* tmpl   = (const float*)d_in[2];
    const float* F2     = (const float*)d_in[3];
    const float* q0     = (const float*)d_in[4];
    const float* alpha0 = (const float*)d_in[5];
    float*       out    = (float*)d_out;

    hipLaunchKernelGGL(ltfgw_wave, dim3(NN * 2), dim3(BLOCK), 0, stream,
                       x, edge, tmpl, F2, q0, alpha0, out);
}

// Round 3
// 1153.726 us; speedup vs baseline: 1.2710x; 1.2350x over previous
//
#include <hip/hip_runtime.h>
#include <math.h>

#define NN   5000
#define DEG  16
#define S    17
#define T    10
#define MN   10
#define D    128
#define NOUT 3
#define NSK  5

#define WPB   5            // waves per block = templates per block
#define BLOCK (WPB * 64)
#define NEG   -3.0e38f

// One wave handles one (node, template) OT problem entirely in registers +
// shuffles. Lane = q*16 + m (q=0..3, m=0..15, m<10 active). Lane owns rows
// s = q+4r for r=0..3 and row 16 (replicated identically across quads,
// counted once via q==0 masking). Block = 5 waves = 5 templates of one node;
// grid = 2 blocks per node.
// __launch_bounds__(BLOCK, 4): VGPR cap 128. (BLOCK, 8) capped at 64 and
// spilled ~everything -> 5 GB/dispatch scratch traffic (round-2 lesson).
__global__ __launch_bounds__(BLOCK, 4) void ltfgw_wave(
    const float* __restrict__ x,        // [N, D]
    const int*   __restrict__ edge,     // [2, N*DEG]
    const float* __restrict__ tmpl,     // [T, MN, MN]
    const float* __restrict__ F2,       // [T, MN, D]
    const float* __restrict__ q0,       // [T, MN]
    const float* __restrict__ alpha0,   // [1]
    float*       __restrict__ out)      // [N, T]
{
    const int n    = blockIdx.x >> 1;
    const int t    = (blockIdx.x & 1) * WPB + (threadIdx.x >> 6);
    const int tid  = threadIdx.x;
    const int w    = tid >> 6;
    const int lane = tid & 63;
    const int q    = lane >> 4;
    const int m    = lane & 15;
    const bool act = (m < MN);
    const int mc   = act ? m : (MN - 1);

    __shared__ int   loc[S];
    __shared__ int   neigh[S][DEG];
    __shared__ float C1s[S][18];              // stride 18: conflict-free row reads
    __shared__ float xsqp[S][8];
    __shared__ float xsqs[S];
    __shared__ float hC1s[S];
    __shared__ float C2l[WPB][MN][17];        // stride 17: conflict-free row reads

    const int* dst = edge + NN * DEG;

    // ---- setup barrier 1: local node list ----
    if (tid < S) loc[tid] = (tid == 0) ? n : dst[n * DEG + tid - 1];
    __syncthreads();

    // ---- neighbor lists + xsq partials (+ per-wave template prep) ----
    if (tid < S * DEG) neigh[tid >> 4][tid & 15] = dst[loc[tid >> 4] * DEG + (tid & 15)];
    if (tid < S * 8) {
        int s0 = tid >> 3, c = tid & 7;
        const float4* xr = (const float4*)(x + (size_t)loc[s0] * D) + c * 4;
        float acc = 0.f;
        #pragma unroll
        for (int i = 0; i < 4; ++i) { float4 v = xr[i]; acc += v.x*v.x + v.y*v.y + v.z*v.z + v.w*v.w; }
        xsqp[s0][c] = acc;
    }
    // q-softmax LSE (per wave, in registers via width-16 shuffles)
    float vq = q0[t * MN + mc];
    float zq = act ? vq : NEG;
    float mq = zq;
    mq = fmaxf(mq, __shfl_xor(mq, 1, 16));
    mq = fmaxf(mq, __shfl_xor(mq, 2, 16));
    mq = fmaxf(mq, __shfl_xor(mq, 4, 16));
    mq = fmaxf(mq, __shfl_xor(mq, 8, 16));
    float sqv = __expf(zq - mq);
    sqv += __shfl_xor(sqv, 1, 16);
    sqv += __shfl_xor(sqv, 2, 16);
    sqv += __shfl_xor(sqv, 4, 16);
    sqv += __shfl_xor(sqv, 8, 16);
    const float lseq = mq + __logf(sqv);
    const float logq = vq - lseq;            // valid for act lanes
    // C2 = softmax(tmpl, axis=1): active lane m of quad 0 does column m
    if (act && q == 0) {
        float v[MN]; float cm = NEG;
        #pragma unroll
        for (int i = 0; i < MN; ++i) { v[i] = tmpl[t * MN * MN + i * MN + m]; cm = fmaxf(cm, v[i]); }
        float ssum = 0.f;
        #pragma unroll
        for (int i = 0; i < MN; ++i) { v[i] = __expf(v[i] - cm); ssum += v[i]; }
        float inv = 1.f / ssum;
        #pragma unroll
        for (int i = 0; i < MN; ++i) C2l[w][i][m] = v[i] * inv;
    }
    __syncthreads();

    // ---- barrier 3: adjacency C1 (needs neigh), xsq reduce ----
    if (tid < S * S) {
        int a = tid / S, b = tid % S;
        int la = loc[a], lb = loc[b];
        bool adj = false;
        #pragma unroll
        for (int k = 0; k < DEG; ++k) adj = adj | (neigh[a][k] == lb) | (neigh[b][k] == la);
        C1s[a][b] = (a != b && adj) ? 1.f : 0.f;
    }
    if (tid < S) {
        float acc = 0.f;
        #pragma unroll
        for (int c = 0; c < 8; ++c) acc += xsqp[tid][c];
        xsqs[tid] = acc;
    }
    __syncthreads();
    if (tid < S) {
        float acc = 0.f;
        #pragma unroll
        for (int j = 0; j < S; ++j) acc += C1s[tid][j];
        hC1s[tid] = acc * (1.f / S);
    }
    __syncthreads();

    // ================= per-wave main (no more barriers) =================
    float C2row[MN];
    #pragma unroll
    for (int k = 0; k < MN; ++k) C2row[k] = C2l[w][mc][k];

    float hC2 = 0.f;
    #pragma unroll
    for (int j = 0; j < MN; ++j) {
        float qj = __expf(q0[t * MN + j] - lseq);
        hC2 += C2row[j] * C2row[j] * qj;
    }

    const float alpha  = 1.f / (1.f + __expf(-alpha0[0]));
    const float oma    = 1.f - alpha;
    const float log_p  = -__logf((float)S);
    const float qm     = __expf(logq);

    int sr[5];
    #pragma unroll
    for (int r = 0; r < 5; ++r) { int s0 = q + 4 * r; sr[r] = (s0 > 16) ? 16 : s0; }

    // M dots: x rows from global (L1/L2-resident: x totals 2.56 MB)
    float dot[5] = {0,0,0,0,0};
    float sqf2 = 0.f;
    {
        const float4* f2p = (const float4*)(F2 + ((size_t)t * MN + mc) * D);
        const float4* xp0 = (const float4*)(x + (size_t)loc[sr[0]] * D);
        const float4* xp1 = (const float4*)(x + (size_t)loc[sr[1]] * D);
        const float4* xp2 = (const float4*)(x + (size_t)loc[sr[2]] * D);
        const float4* xp3 = (const float4*)(x + (size_t)loc[sr[3]] * D);
        const float4* xp4 = (const float4*)(x + (size_t)loc[sr[4]] * D);
        #pragma unroll 4
        for (int d4 = 0; d4 < D / 4; ++d4) {
            float4 f = f2p[d4];
            sqf2 += f.x*f.x + f.y*f.y + f.z*f.z + f.w*f.w;
            float4 v;
            v = xp0[d4]; dot[0] += f.x*v.x + f.y*v.y + f.z*v.z + f.w*v.w;
            v = xp1[d4]; dot[1] += f.x*v.x + f.y*v.y + f.z*v.z + f.w*v.w;
            v = xp2[d4]; dot[2] += f.x*v.x + f.y*v.y + f.z*v.z + f.w*v.w;
            v = xp3[d4]; dot[3] += f.x*v.x + f.y*v.y + f.z*v.z + f.w*v.w;
            v = xp4[d4]; dot[4] += f.x*v.x + f.y*v.y + f.z*v.z + f.w*v.w;
        }
    }
    float M_[5], cC[5];
    #pragma unroll
    for (int r = 0; r < 5; ++r) {
        M_[r] = xsqs[sr[r]] + sqf2 - 2.f * dot[r];
        cC[r] = hC1s[sr[r]] + hC2;
    }

    float G[5];
    #pragma unroll
    for (int r = 0; r < 5; ++r) G[r] = qm * (1.f / S);   // G0 = p q^T
    float lk[5], a_[5], b_ = 0.f, tens[5];

    for (int o = 0; o <= NOUT; ++o) {
        // H[j][m] = sum_k G[j][k] * C2[m][k]; lane holds rows of its quad
        float H[5];
        #pragma unroll
        for (int r = 0; r < 5; ++r) {
            float h = 0.f;
            #pragma unroll
            for (int k = 0; k < MN; ++k) h += __shfl(G[r], k, 16) * C2row[k];
            H[r] = h;
        }
        // tens[s][m] = sum_j C1[s][j] * H[j][m]; gather H[j][m] cross-quad
        #pragma unroll
        for (int r = 0; r < 5; ++r) tens[r] = 0.f;
        #pragma unroll
        for (int j = 0; j < 16; ++j) {
            float hj = __shfl(H[j >> 2], ((j & 3) << 4) + m, 64);
            #pragma unroll
            for (int r = 0; r < 5; ++r) tens[r] += C1s[sr[r]][j] * hj;
        }
        {   // j = 16: replicated locally in every quad
            float hj = H[4];
            #pragma unroll
            for (int r = 0; r < 5; ++r) tens[r] += C1s[sr[r]][16] * hj;
        }
        if (o == NOUT) break;   // final tens computed with final G

        #pragma unroll
        for (int r = 0; r < 5; ++r) {
            float cost = oma * M_[r] + 2.f * alpha * (cC[r] - 2.f * tens[r]);
            lk[r] = -10.f * cost;              // logK = -cost/EPS, EPS=0.1
        }
        b_ = 0.f;
        for (int it = 0; it < NSK; ++it) {
            // a-update: a_s = log_p - LSE_m(lk + b)
            float z[5], mx[5], sm[5];
            #pragma unroll
            for (int r = 0; r < 5; ++r) { z[r] = act ? (lk[r] + b_) : NEG; mx[r] = z[r]; }
            #pragma unroll
            for (int r = 0; r < 5; ++r) mx[r] = fmaxf(mx[r], __shfl_xor(mx[r], 1, 16));
            #pragma unroll
            for (int r = 0; r < 5; ++r) mx[r] = fmaxf(mx[r], __shfl_xor(mx[r], 2, 16));
            #pragma unroll
            for (int r = 0; r < 5; ++r) mx[r] = fmaxf(mx[r], __shfl_xor(mx[r], 4, 16));
            #pragma unroll
            for (int r = 0; r < 5; ++r) mx[r] = fmaxf(mx[r], __shfl_xor(mx[r], 8, 16));
            #pragma unroll
            for (int r = 0; r < 5; ++r) sm[r] = __expf(z[r] - mx[r]);
            #pragma unroll
            for (int r = 0; r < 5; ++r) sm[r] += __shfl_xor(sm[r], 1, 16);
            #pragma unroll
            for (int r = 0; r < 5; ++r) sm[r] += __shfl_xor(sm[r], 2, 16);
            #pragma unroll
            for (int r = 0; r < 5; ++r) sm[r] += __shfl_xor(sm[r], 4, 16);
            #pragma unroll
            for (int r = 0; r < 5; ++r) sm[r] += __shfl_xor(sm[r], 8, 16);
            #pragma unroll
            for (int r = 0; r < 5; ++r) a_[r] = log_p - mx[r] - __logf(sm[r]);
            // b-update: b_m = logq - LSE_s(lk + a)
            float w0 = lk[0] + a_[0], w1 = lk[1] + a_[1], w2 = lk[2] + a_[2];
            float w3 = lk[3] + a_[3];
            float w4 = (q == 0) ? (lk[4] + a_[4]) : NEG;  // row 16 counted once
            float mb = fmaxf(fmaxf(fmaxf(w0, w1), fmaxf(w2, w3)), w4);
            mb = fmaxf(mb, __shfl_xor(mb, 16, 64));
            mb = fmaxf(mb, __shfl_xor(mb, 32, 64));
            float sb = __expf(w0 - mb) + __expf(w1 - mb) + __expf(w2 - mb)
                     + __expf(w3 - mb) + __expf(w4 - mb);
            sb += __shfl_xor(sb, 16, 64);
            sb += __shfl_xor(sb, 32, 64);
            b_ = logq - mb - __logf(sb);
        }
        #pragma unroll
        for (int r = 0; r < 5; ++r) G[r] = __expf(lk[r] + a_[r] + b_);
    }

    // dist = sum_{s,m} G * ((1-a) M + a tens)
    float val = 0.f;
    #pragma unroll
    for (int r = 0; r < 5; ++r) {
        float te = cC[r] - 2.f * tens[r];
        float v  = G[r] * (oma * M_[r] + alpha * te);
        bool valid = act && (r < 4 || q == 0);
        val += valid ? v : 0.f;
    }
    val += __shfl_xor(val, 1, 64);
    val += __shfl_xor(val, 2, 64);
    val += __shfl_xor(val, 4, 64);
    val += __shfl_xor(val, 8, 64);
    val += __shfl_xor(val, 16, 64);
    val += __shfl_xor(val, 32, 64);
    if (lane == 0) out[n * T + t] = val;
}

extern "C" void kernel_launch(void* const* d_in, const int* in_sizes, int n_in,
                              void* d_out, int out_size, void* d_ws, size_t ws_size,
                              hipStream_t stream) {
    const float* x      = (const float*)d_in[0];
    const int*   edge   = (const int*)  d_in[1];
    const float* tmpl   = (const float*)d_in[2];
    const float* F2     = (const float*)d_in[3];
    const float* q0     = (const float*)d_in[4];
    const float* alpha0 = (const float*)d_in[5];
    float*       out    = (float*)d_out;

    hipLaunchKernelGGL(ltfgw_wave, dim3(NN * 2), dim3(BLOCK), 0, stream,
                       x, edge, tmpl, F2, q0, alpha0, out);
}

// Round 5
// 958.059 us; speedup vs baseline: 1.5306x; 1.2042x over previous
//
#include <hip/hip_runtime.h>
#include <math.h>

#define NN   5000
#define DEG  16
#define S    17
#define T    10
#define MN   10
#define D    128
#define NOUT 3
#define NSK  5

#define WPB   5            // waves per block = templates per block
#define BLOCK (WPB * 64)
#define NEG   -3.0e38f

__device__ __forceinline__ float fast_rcp(float x) { return __builtin_amdgcn_rcpf(x); }

// One wave = one (node, template) OT problem in registers + shuffles.
// Lane = q*16 + m (q=0..3 quad, m=0..15 col, m<10 active). Lane owns rows
// s = q+4r (r=0..3) plus row 16 (replicated across quads, counted once).
// Sinkhorn runs in exp domain after one per-outer row-max stabilization:
// K~ = exp(logK - rowmax); u = p*rcp(sum_m K~ v); v = q*rcp(sum_s K~ u);
// G = K~ u v  — exactly the reference log-domain iteration (row scale
// cancels: u absorbs exp(+rm_s), K~ carries exp(-rm_s)).
// Round-4 NaN lesson: inactive lanes (m>=10) see cs==0 -> rcp(0)=inf ->
// 0*inf=NaN next iteration. v_ must be masked to 0 on inactive lanes.
// __launch_bounds__: block size ONLY — any min-waves hint snapped VGPRs to
// 64/32 and spilled GBs of scratch (rounds 2-3 lesson).
__global__ __launch_bounds__(BLOCK) void ltfgw_wave(
    const float* __restrict__ x,        // [N, D]
    const int*   __restrict__ edge,     // [2, N*DEG]
    const float* __restrict__ tmpl,     // [T, MN, MN]
    const float* __restrict__ F2,       // [T, MN, D]
    const float* __restrict__ q0,       // [T, MN]
    const float* __restrict__ alpha0,   // [1]
    float*       __restrict__ out)      // [N, T]
{
    const int n    = blockIdx.x >> 1;
    const int t    = (blockIdx.x & 1) * WPB + (threadIdx.x >> 6);
    const int tid  = threadIdx.x;
    const int w    = tid >> 6;
    const int lane = tid & 63;
    const int q    = lane >> 4;
    const int m    = lane & 15;
    const bool act = (m < MN);
    const int mc   = act ? m : (MN - 1);

    __shared__ int   loc[S];
    __shared__ int   neigh[S][DEG];
    __shared__ float C1s[S][18];              // stride 18: conflict-free row reads
    __shared__ float xsqp[S][8];
    __shared__ float xsqs[S];
    __shared__ float hC1s[S];
    __shared__ float C2l[WPB][MN][17];        // stride 17: conflict-free row reads

    const int* dst = edge + NN * DEG;

    // ---- barrier 1: local node list ----
    if (tid < S) loc[tid] = (tid == 0) ? n : dst[n * DEG + tid - 1];
    __syncthreads();

    // ---- neighbor lists + xsq partials + per-wave template prep ----
    if (tid < S * DEG) neigh[tid >> 4][tid & 15] = dst[loc[tid >> 4] * DEG + (tid & 15)];
    if (tid < S * 8) {
        int s0 = tid >> 3, c = tid & 7;
        const float4* xr = (const float4*)(x + (size_t)loc[s0] * D) + c * 4;
        float acc = 0.f;
        #pragma unroll
        for (int i = 0; i < 4; ++i) { float4 v = xr[i]; acc += v.x*v.x + v.y*v.y + v.z*v.z + v.w*v.w; }
        xsqp[s0][c] = acc;
    }
    // q-softmax LSE (width-16 shuffles, per wave)
    float vq = q0[t * MN + mc];
    float zq = act ? vq : NEG;
    float mq = zq;
    mq = fmaxf(mq, __shfl_xor(mq, 1, 16));
    mq = fmaxf(mq, __shfl_xor(mq, 2, 16));
    mq = fmaxf(mq, __shfl_xor(mq, 4, 16));
    mq = fmaxf(mq, __shfl_xor(mq, 8, 16));
    float sqv = __expf(zq - mq);
    sqv += __shfl_xor(sqv, 1, 16);
    sqv += __shfl_xor(sqv, 2, 16);
    sqv += __shfl_xor(sqv, 4, 16);
    sqv += __shfl_xor(sqv, 8, 16);
    const float lseq = mq + __logf(sqv);
    const float logq = vq - lseq;
    const float qm   = __expf(logq);          // q_m for this lane's column
    // C2 = softmax(tmpl, axis=1): active lane m of quad 0 does column m
    if (act && q == 0) {
        float v[MN]; float cm = NEG;
        #pragma unroll
        for (int i = 0; i < MN; ++i) { v[i] = tmpl[t * MN * MN + i * MN + m]; cm = fmaxf(cm, v[i]); }
        float ssum = 0.f;
        #pragma unroll
        for (int i = 0; i < MN; ++i) { v[i] = __expf(v[i] - cm); ssum += v[i]; }
        float inv = 1.f / ssum;
        #pragma unroll
        for (int i = 0; i < MN; ++i) C2l[w][i][m] = v[i] * inv;
    }
    __syncthreads();

    // ---- barrier 2/3: adjacency C1, xsq reduce, hC1 ----
    if (tid < S * S) {
        int a = tid / S, b = tid % S;
        int la = loc[a], lb = loc[b];
        bool adj = false;
        #pragma unroll
        for (int k = 0; k < DEG; ++k) adj = adj | (neigh[a][k] == lb) | (neigh[b][k] == la);
        C1s[a][b] = (a != b && adj) ? 1.f : 0.f;
    }
    if (tid < S) {
        float acc = 0.f;
        #pragma unroll
        for (int c = 0; c < 8; ++c) acc += xsqp[tid][c];
        xsqs[tid] = acc;
    }
    __syncthreads();
    if (tid < S) {
        float acc = 0.f;
        #pragma unroll
        for (int j = 0; j < S; ++j) acc += C1s[tid][j];
        hC1s[tid] = acc * (1.f / S);
    }
    __syncthreads();

    // ================= per-wave main (no more barriers) =================
    float C2row[MN];
    #pragma unroll
    for (int k = 0; k < MN; ++k) C2row[k] = C2l[w][mc][k];

    float hC2 = 0.f;
    #pragma unroll
    for (int j = 0; j < MN; ++j)
        hC2 += C2row[j] * C2row[j] * __shfl(qm, j, 16);

    const float alpha = 1.f / (1.f + __expf(-alpha0[0]));
    const float oma   = 1.f - alpha;
    const float p_    = 1.f / (float)S;
    const float fa4   = 40.f * alpha;         // lk = lkP + 40*alpha*tens

    int sr[5];
    #pragma unroll
    for (int r = 0; r < 5; ++r) { int s0 = q + 4 * r; sr[r] = (s0 > 16) ? 16 : s0; }

    // M dots: x rows from global (L1/L2-resident; broadcast within groups)
    float dot[5] = {0,0,0,0,0};
    float sqf2 = 0.f;
    {
        const float4* f2p = (const float4*)(F2 + ((size_t)t * MN + mc) * D);
        const float4* xp0 = (const float4*)(x + (size_t)loc[sr[0]] * D);
        const float4* xp1 = (const float4*)(x + (size_t)loc[sr[1]] * D);
        const float4* xp2 = (const float4*)(x + (size_t)loc[sr[2]] * D);
        const float4* xp3 = (const float4*)(x + (size_t)loc[sr[3]] * D);
        const float4* xp4 = (const float4*)(x + (size_t)loc[sr[4]] * D);
        #pragma unroll 4
        for (int d4 = 0; d4 < D / 4; ++d4) {
            float4 f = f2p[d4];
            sqf2 += f.x*f.x + f.y*f.y + f.z*f.z + f.w*f.w;
            float4 v;
            v = xp0[d4]; dot[0] += f.x*v.x + f.y*v.y + f.z*v.z + f.w*v.w;
            v = xp1[d4]; dot[1] += f.x*v.x + f.y*v.y + f.z*v.z + f.w*v.w;
            v = xp2[d4]; dot[2] += f.x*v.x + f.y*v.y + f.z*v.z + f.w*v.w;
            v = xp3[d4]; dot[3] += f.x*v.x + f.y*v.y + f.z*v.z + f.w*v.w;
            v = xp4[d4]; dot[4] += f.x*v.x + f.y*v.y + f.z*v.z + f.w*v.w;
        }
    }
    // lkP = -10 * ((1-a)*M + 2a*constC); logK = lkP + 40a*tens
    float lkP[5];
    #pragma unroll
    for (int r = 0; r < 5; ++r) {
        float M_ = xsqs[sr[r]] + sqf2 - 2.f * dot[r];
        float cC = hC1s[sr[r]] + hC2;
        lkP[r] = -10.f * (oma * M_ + 2.f * alpha * cC);
    }

    float G[5];
    #pragma unroll
    for (int r = 0; r < 5; ++r) G[r] = act ? (qm * p_) : 0.f;   // G0 = p q^T
    float tens[5];

    for (int o = 0; o <= NOUT; ++o) {
        // H[j][m] = sum_k G[j][k] * C2[m][k]
        float H[5];
        #pragma unroll
        for (int r = 0; r < 5; ++r) {
            float h = 0.f;
            #pragma unroll
            for (int k = 0; k < MN; ++k) h += __shfl(G[r], k, 16) * C2row[k];
            H[r] = h;
        }
        // tens[s][m] = sum_j C1[s][j] * H[j][m]
        #pragma unroll
        for (int r = 0; r < 5; ++r) tens[r] = 0.f;
        #pragma unroll
        for (int j = 0; j < 16; ++j) {
            float hj = __shfl(H[j >> 2], ((j & 3) << 4) + m, 64);
            #pragma unroll
            for (int r = 0; r < 5; ++r) tens[r] += C1s[sr[r]][j] * hj;
        }
        {
            float hj = H[4];   // row 16: replicated locally in every quad
            #pragma unroll
            for (int r = 0; r < 5; ++r) tens[r] += C1s[sr[r]][16] * hj;
        }
        if (o == NOUT) break;

        // logK = lkP + 40*alpha*tens; stabilize by row max; K~ = exp(logK - rm)
        float Kt[5];
        #pragma unroll
        for (int r = 0; r < 5; ++r) {
            float lk = fmaf(fa4, tens[r], lkP[r]);
            float z  = act ? lk : NEG;
            float rm = z;
            rm = fmaxf(rm, __shfl_xor(rm, 1, 16));
            rm = fmaxf(rm, __shfl_xor(rm, 2, 16));
            rm = fmaxf(rm, __shfl_xor(rm, 4, 16));
            rm = fmaxf(rm, __shfl_xor(rm, 8, 16));
            Kt[r] = act ? __expf(lk - rm) : 0.f;
        }
        // exp-domain Sinkhorn: u = p*rcp(K~ v), v = q*rcp(K~^T u)
        float v_ = act ? 1.f : 0.f;
        float u_[5];
        #pragma unroll
        for (int it = 0; it < NSK; ++it) {
            #pragma unroll
            for (int r = 0; r < 5; ++r) {
                float t0 = Kt[r] * v_;
                t0 += __shfl_xor(t0, 1, 16);
                t0 += __shfl_xor(t0, 2, 16);
                t0 += __shfl_xor(t0, 4, 16);
                t0 += __shfl_xor(t0, 8, 16);
                u_[r] = p_ * fast_rcp(t0);
            }
            float cs = Kt[0]*u_[0] + Kt[1]*u_[1] + Kt[2]*u_[2] + Kt[3]*u_[3];
            cs += (q == 0) ? Kt[4]*u_[4] : 0.f;   // row 16 counted once
            cs += __shfl_xor(cs, 16, 64);
            cs += __shfl_xor(cs, 32, 64);
            // mask: inactive lanes have cs==0 -> rcp(0)=inf -> 0*inf=NaN
            v_ = act ? (qm * fast_rcp(cs)) : 0.f;
        }
        #pragma unroll
        for (int r = 0; r < 5; ++r) G[r] = Kt[r] * u_[r] * v_;
    }

    // dist = sum G * ((1-a)M + a*(constC - 2*tens))
    //      = sum G * (-0.1*lkP - a*cC - 2a*tens)
    float val = 0.f;
    #pragma unroll
    for (int r = 0; r < 5; ++r) {
        float cC = hC1s[sr[r]] + hC2;
        float integ = -0.1f * lkP[r] - alpha * cC - 2.f * alpha * tens[r];
        float v  = G[r] * integ;
        bool valid = act && (r < 4 || q == 0);
        val += valid ? v : 0.f;
    }
    val += __shfl_xor(val, 1, 64);
    val += __shfl_xor(val, 2, 64);
    val += __shfl_xor(val, 4, 64);
    val += __shfl_xor(val, 8, 64);
    val += __shfl_xor(val, 16, 64);
    val += __shfl_xor(val, 32, 64);
    if (lane == 0) out[n * T + t] = val;
}

extern "C" void kernel_launch(void* const* d_in, const int* in_sizes, int n_in,
                              void* d_out, int out_size, void* d_ws, size_t ws_size,
                              hipStream_t stream) {
    const float* x      = (const float*)d_in[0];
    const int*   edge   = (const int*)  d_in[1];
    const float* tmpl   = (const float*)d_in[2];
    const float* F2     = (const float*)d_in[3];
    const float* q0     = (const float*)d_in[4];
    const float* alpha0 = (const float*)d_in[5];
    float*       out    = (float*)d_out;

    hipLaunchKernelGGL(ltfgw_wave, dim3(NN * 2), dim3(BLOCK), 0, stream,
                       x, edge, tmpl, F2, q0, alpha0, out);
}

// Round 6
// 618.844 us; speedup vs baseline: 2.3696x; 1.5481x over previous
//
#include <hip/hip_runtime.h>
#include <math.h>

#define NN   5000
#define DEG  16
#define S    17
#define T    10
#define MN   10
#define D    128
#define NOUT 3
#define NSK  5

#define WPB   5            // waves per block = templates per block
#define BLOCK (WPB * 64)
#define NEG   -3.0e38f

__device__ __forceinline__ float fast_rcp(float x) { return __builtin_amdgcn_rcpf(x); }

// DPP row_ror:k — pure-VALU cross-lane within each 16-lane row.
// Replaces ds_bpermute shuffles (LDS pipe, ~35cyc latency) with ~2cyc VALU.
template <int CTRL>
__device__ __forceinline__ float dpp_movf(float v) {
    return __int_as_float(__builtin_amdgcn_update_dpp(
        0, __float_as_int(v), CTRL, 0xF, 0xF, true));
}
__device__ __forceinline__ int dpp_movi(int v) {
    return __builtin_amdgcn_update_dpp(0, v, 0x121, 0xF, 0xF, true);
}
// rotations by 1,2,4,8 cover all 16 offsets -> full-row sum/max in all lanes
__device__ __forceinline__ float rowsum16(float v) {
    v += dpp_movf<0x121>(v);
    v += dpp_movf<0x122>(v);
    v += dpp_movf<0x124>(v);
    v += dpp_movf<0x128>(v);
    return v;
}
__device__ __forceinline__ float rowmax16(float v) {
    v = fmaxf(v, dpp_movf<0x121>(v));
    v = fmaxf(v, dpp_movf<0x122>(v));
    v = fmaxf(v, dpp_movf<0x124>(v));
    v = fmaxf(v, dpp_movf<0x128>(v));
    return v;
}

// One wave = one (node, template) OT problem. Lane = q*16+m; lane owns rows
// s = q+4r (r=0..3) + row 16 (replicated across quads, counted once).
// All width-16 reductions via DPP (VALU). H = G*C2^T via DPP rotation with
// C2rot[i] = C2[mc][sigma^i(m)] (sigma measured at runtime -> direction-proof).
// C1 rows as per-lane bitmasks (atomicOr-built). Remaining LDS-pipe ops per
// wave: ~130 (was ~1000 in round 5 -> latency-bound at VALUBusy 29%).
// __launch_bounds__: block size ONLY (rounds 2-3: min-waves hint => spills).
__global__ __launch_bounds__(BLOCK) void ltfgw_wave(
    const float* __restrict__ x,        // [N, D]
    const int*   __restrict__ edge,     // [2, N*DEG]
    const float* __restrict__ tmpl,     // [T, MN, MN]
    const float* __restrict__ F2,       // [T, MN, D]
    const float* __restrict__ q0,       // [T, MN]
    const float* __restrict__ alpha0,   // [1]
    float*       __restrict__ out)      // [N, T]
{
    const int n    = blockIdx.x >> 1;
    const int t    = (blockIdx.x & 1) * WPB + (threadIdx.x >> 6);
    const int tid  = threadIdx.x;
    const int w    = tid >> 6;
    const int lane = tid & 63;
    const int q    = lane >> 4;
    const int m    = lane & 15;
    const bool act = (m < MN);
    const int mc   = act ? m : (MN - 1);

    __shared__ int      loc[S];
    __shared__ int      neigh[S][DEG];
    __shared__ unsigned C1m[S];               // adjacency rows as bitmasks
    __shared__ float    xsqp[S][8];
    __shared__ float    xsqs[S];
    __shared__ float    C2l[WPB][MN][17];     // stride 17: conflict-free

    const int* dst = edge + NN * DEG;

    // ---- barrier 1: local node list + mask init ----
    if (tid < S) { loc[tid] = (tid == 0) ? n : dst[n * DEG + tid - 1]; C1m[tid] = 0u; }
    __syncthreads();

    // ---- phase B: neighbor lists, xsq partials, C2 softmax, q softmax ----
    if (tid < S * DEG) neigh[tid >> 4][tid & 15] = dst[loc[tid >> 4] * DEG + (tid & 15)];
    if (tid < S * 8) {
        int s0 = tid >> 3, c = tid & 7;
        const float4* xr = (const float4*)(x + (size_t)loc[s0] * D) + c * 4;
        float acc = 0.f;
        #pragma unroll
        for (int i = 0; i < 4; ++i) { float4 v = xr[i]; acc += v.x*v.x + v.y*v.y + v.z*v.z + v.w*v.w; }
        xsqp[s0][c] = acc;
    }
    // q = softmax(q0[t]) via DPP row reduction (all lanes)
    float vq = q0[t * MN + mc];
    float zq = act ? vq : NEG;
    float mq = rowmax16(zq);
    float sq = rowsum16(__expf(zq - mq));     // inactive: exp(NEG-mq)=0
    const float qm = __expf(vq - (mq + __logf(sq)));   // valid on act lanes
    // C2 = softmax(tmpl, axis=1): active lane m of quad 0 does column m
    if (act && q == 0) {
        float v[MN]; float cm = NEG;
        #pragma unroll
        for (int i = 0; i < MN; ++i) { v[i] = tmpl[t * MN * MN + i * MN + m]; cm = fmaxf(cm, v[i]); }
        float ssum = 0.f;
        #pragma unroll
        for (int i = 0; i < MN; ++i) { v[i] = __expf(v[i] - cm); ssum += v[i]; }
        float inv = 1.f / ssum;
        #pragma unroll
        for (int i = 0; i < MN; ++i) C2l[w][i][m] = v[i] * inv;
    }
    __syncthreads();

    // ---- phase C: adjacency -> bitmasks (atomicOr), xsq reduce ----
    if (tid < S * S) {
        int a = tid / S, b = tid % S;
        int la = loc[a], lb = loc[b];
        bool adj = false;
        #pragma unroll
        for (int k = 0; k < DEG; ++k) adj = adj | (neigh[a][k] == lb) | (neigh[b][k] == la);
        if (a != b && adj) atomicOr(&C1m[a], 1u << b);
    }
    if (tid >= S * S && tid < S * S + S) {
        int s0 = tid - S * S;
        float acc = 0.f;
        #pragma unroll
        for (int c = 0; c < 8; ++c) acc += xsqp[s0][c];
        xsqs[s0] = acc;
    }
    __syncthreads();

    // ================= per-wave main (no more barriers) =================
    int sr[5];
    #pragma unroll
    for (int r = 0; r < 5; ++r) { int s0 = q + 4 * r; sr[r] = (s0 > 16) ? 16 : s0; }
    unsigned msk[5]; float hC1r[5];
    #pragma unroll
    for (int r = 0; r < 5; ++r) {
        msk[r]  = C1m[sr[r]];
        hC1r[r] = (float)__popc(msk[r]) * (1.f / (float)S);
    }

    // M dots: x rows from global (L1/L2-resident)
    float dot[5] = {0,0,0,0,0};
    float sqf2 = 0.f;
    {
        const float4* f2p = (const float4*)(F2 + ((size_t)t * MN + mc) * D);
        const float4* xp0 = (const float4*)(x + (size_t)loc[sr[0]] * D);
        const float4* xp1 = (const float4*)(x + (size_t)loc[sr[1]] * D);
        const float4* xp2 = (const float4*)(x + (size_t)loc[sr[2]] * D);
        const float4* xp3 = (const float4*)(x + (size_t)loc[sr[3]] * D);
        const float4* xp4 = (const float4*)(x + (size_t)loc[sr[4]] * D);
        #pragma unroll 4
        for (int d4 = 0; d4 < D / 4; ++d4) {
            float4 f = f2p[d4];
            sqf2 += f.x*f.x + f.y*f.y + f.z*f.z + f.w*f.w;
            float4 v;
            v = xp0[d4]; dot[0] += f.x*v.x + f.y*v.y + f.z*v.z + f.w*v.w;
            v = xp1[d4]; dot[1] += f.x*v.x + f.y*v.y + f.z*v.z + f.w*v.w;
            v = xp2[d4]; dot[2] += f.x*v.x + f.y*v.y + f.z*v.z + f.w*v.w;
            v = xp3[d4]; dot[3] += f.x*v.x + f.y*v.y + f.z*v.z + f.w*v.w;
            v = xp4[d4]; dot[4] += f.x*v.x + f.y*v.y + f.z*v.z + f.w*v.w;
        }
    }

    // C2rot[i] = C2[mc][sigma^i(m)] — sigma probed with the same DPP op,
    // so the rotated-G dot product below is rotation-direction-proof.
    float C2rot[16];
    {
        int li = m;
        #pragma unroll
        for (int i = 0; i < 16; ++i) {
            C2rot[i] = (li < MN) ? C2l[w][mc][li] : 0.f;
            if (i < 15) li = dpp_movi(li);
        }
    }
    // hC2 = sum_j C2[mc][j]^2 q[j] via the same rotation pairing
    float hC2 = 0.f;
    {
        float qrot = qm;
        #pragma unroll
        for (int i = 0; i < 16; ++i) {
            hC2 = fmaf(C2rot[i] * C2rot[i], qrot, hC2);
            if (i < 15) qrot = dpp_movf<0x121>(qrot);
        }
    }

    const float alpha = 1.f / (1.f + __expf(-alpha0[0]));
    const float oma   = 1.f - alpha;
    const float p_    = 1.f / (float)S;
    const float fa4   = 40.f * alpha;         // logK = lkP + 40*alpha*tens

    float lkP[5];
    #pragma unroll
    for (int r = 0; r < 5; ++r) {
        float M_ = xsqs[sr[r]] + sqf2 - 2.f * dot[r];
        float cC = hC1r[r] + hC2;
        lkP[r] = -10.f * (oma * M_ + 2.f * alpha * cC);
    }

    float G[5];
    #pragma unroll
    for (int r = 0; r < 5; ++r) G[r] = act ? (qm * p_) : 0.f;   // G0 = p q^T
    float tens[5], Kt[5], u_[5], v_;

    for (int o = 0; o <= NOUT; ++o) {
        // H[s=own rows][m] = sum_k G[s][k]*C2[m][k] via DPP rotation (VALU-only)
        float H[5];
        #pragma unroll
        for (int r = 0; r < 5; ++r) {
            float h = 0.f, Gr = G[r];
            #pragma unroll
            for (int i = 0; i < 16; ++i) {
                h = fmaf(Gr, C2rot[i], h);
                if (i < 15) Gr = dpp_movf<0x121>(Gr);
            }
            H[r] = h;
        }
        // tens[s][m] = sum_j C1[s][j]*H[j][m]; C1 row = bitmask, H gathered
        #pragma unroll
        for (int r = 0; r < 5; ++r) tens[r] = 0.f;
        #pragma unroll
        for (int j = 0; j < 16; ++j) {
            float hj = __shfl(H[j >> 2], ((j & 3) << 4) + m, 64);
            #pragma unroll
            for (int r = 0; r < 5; ++r) tens[r] += ((msk[r] >> j) & 1u) ? hj : 0.f;
        }
        {
            float hj = H[4];   // row 16: replicated locally in every quad
            #pragma unroll
            for (int r = 0; r < 5; ++r) tens[r] += ((msk[r] >> 16) & 1u) ? hj : 0.f;
        }
        if (o == NOUT) break;

        // K~ = exp(logK - rowmax) (rowmax via DPP)
        #pragma unroll
        for (int r = 0; r < 5; ++r) {
            float lk = fmaf(fa4, tens[r], lkP[r]);
            float rm = rowmax16(act ? lk : NEG);
            Kt[r] = act ? __expf(lk - rm) : 0.f;
        }
        // exp-domain Sinkhorn: u = p*rcp(K~ v), v = q*rcp(K~^T u)
        v_ = act ? 1.f : 0.f;
        #pragma unroll
        for (int it = 0; it < NSK; ++it) {
            #pragma unroll
            for (int r = 0; r < 5; ++r) {
                float t0 = rowsum16(Kt[r] * v_);
                u_[r] = p_ * fast_rcp(t0);
            }
            float cs = Kt[0]*u_[0] + Kt[1]*u_[1] + Kt[2]*u_[2] + Kt[3]*u_[3];
            cs += (q == 0) ? Kt[4]*u_[4] : 0.f;   // row 16 counted once
            cs += __shfl_xor(cs, 16, 64);
            cs += __shfl_xor(cs, 32, 64);
            v_ = act ? (qm * fast_rcp(cs)) : 0.f; // mask: rcp(0)=inf -> NaN
        }
        #pragma unroll
        for (int r = 0; r < 5; ++r) G[r] = Kt[r] * u_[r] * v_;
    }

    // dist = sum G * (-0.1*lkP - a*cC - 2a*tens)
    float val = 0.f;
    #pragma unroll
    for (int r = 0; r < 5; ++r) {
        float cC = hC1r[r] + hC2;
        float integ = -0.1f * lkP[r] - alpha * cC - 2.f * alpha * tens[r];
        bool valid = act && (r < 4 || q == 0);
        val += valid ? G[r] * integ : 0.f;
    }
    val = rowsum16(val);
    val += __shfl_xor(val, 16, 64);
    val += __shfl_xor(val, 32, 64);
    if (lane == 0) out[n * T + t] = val;
}

extern "C" void kernel_launch(void* const* d_in, const int* in_sizes, int n_in,
                              void* d_out, int out_size, void* d_ws, size_t ws_size,
                              hipStream_t stream) {
    const float* x      = (const float*)d_in[0];
    const int*   edge   = (const int*)  d_in[1];
    const float* tmpl   = (const float*)d_in[2];
    const float* F2     = (const float*)d_in[3];
    const float* q0     = (const float*)d_in[4];
    const float* alpha0 = (const float*)d_in[5];
    float*       out    = (float*)d_out;

    hipLaunchKernelGGL(ltfgw_wave, dim3(NN * 2), dim3(BLOCK), 0, stream,
                       x, edge, tmpl, F2, q0, alpha0, out);
}

// Round 7
// 465.017 us; speedup vs baseline: 3.1534x; 1.3308x over previous
//
#include <hip/hip_runtime.h>
#include <math.h>

#define NN   5000
#define DEG  16
#define S    17
#define T    10
#define MN   10
#define D    128
#define NOUT 3
#define NSK  5

#define WPB   2            // waves per block = templates per block
#define BLOCK (WPB * 64)
#define NEG   -3.0e38f

__device__ __forceinline__ float fast_rcp(float x) { return __builtin_amdgcn_rcpf(x); }

// DPP row_ror:k — pure-VALU cross-lane within each 16-lane row (~2cyc vs
// ds_bpermute's LDS-pipe ~35cyc latency).
template <int CTRL>
__device__ __forceinline__ float dpp_movf(float v) {
    return __int_as_float(__builtin_amdgcn_update_dpp(
        0, __float_as_int(v), CTRL, 0xF, 0xF, true));
}
__device__ __forceinline__ int dpp_movi(int v) {
    return __builtin_amdgcn_update_dpp(0, v, 0x121, 0xF, 0xF, true);
}
__device__ __forceinline__ float rowsum16(float v) {
    v += dpp_movf<0x121>(v);
    v += dpp_movf<0x122>(v);
    v += dpp_movf<0x124>(v);
    v += dpp_movf<0x128>(v);
    return v;
}
__device__ __forceinline__ float rowmax16(float v) {
    v = fmaxf(v, dpp_movf<0x121>(v));
    v = fmaxf(v, dpp_movf<0x122>(v));
    v = fmaxf(v, dpp_movf<0x124>(v));
    v = fmaxf(v, dpp_movf<0x128>(v));
    return v;
}

// One wave = one (node, template) OT problem. Lane = q*16+m; lane owns rows
// s = q+4r (r=0..3) + row 16 (replicated across quads, counted once).
// Round-7 changes vs round 6 (619us, VALUBusy 65%, Occupancy 25%):
//  - 128-thread blocks (2 waves): finer occupancy granularity than 5-wave
//    blocks which sat at ~1.6 blocks/CU.
//  - outer-0 tens is analytic: G0 = p q^T => H0[j][m] = p*sum_k q_k C2[m][k]
//    (row-independent) => tens0[r] = p*qC2m*popc(mask). Skips one full
//    H-rotation + tens gather (~250 VALU + 17 bpermutes).
//  - Sinkhorn p-folding: u=p*û with û=rcp(sum Kt v); v=(17q)*rcp(sum Kt û);
//    G = Kt*û*(p*v). Identical algebra, 5 fewer muls per u-update.
// __launch_bounds__: block size ONLY (rounds 2-3: min-waves hint => spills).
__global__ __launch_bounds__(BLOCK) void ltfgw_wave(
    const float* __restrict__ x,        // [N, D]
    const int*   __restrict__ edge,     // [2, N*DEG]
    const float* __restrict__ tmpl,     // [T, MN, MN]
    const float* __restrict__ F2,       // [T, MN, D]
    const float* __restrict__ q0,       // [T, MN]
    const float* __restrict__ alpha0,   // [1]
    float*       __restrict__ out)      // [N, T]
{
    const int blk  = blockIdx.x;
    const int n    = blk / 5;
    const int tp   = blk % 5;
    const int tid  = threadIdx.x;
    const int w    = tid >> 6;
    const int t    = tp * 2 + w;
    const int lane = tid & 63;
    const int q    = lane >> 4;
    const int m    = lane & 15;
    const bool act = (m < MN);
    const int mc   = act ? m : (MN - 1);

    __shared__ int      loc[S];
    __shared__ int      neigh[S][DEG];
    __shared__ unsigned C1m[S];               // adjacency rows as bitmasks
    __shared__ float    xsqp[S][8];
    __shared__ float    xsqs[S];
    __shared__ float    C2l[WPB][MN][17];     // stride 17: conflict-free

    const int* dst = edge + NN * DEG;

    // ---- barrier 1: local node list + mask init ----
    if (tid < S) { loc[tid] = (tid == 0) ? n : dst[n * DEG + tid - 1]; C1m[tid] = 0u; }
    __syncthreads();

    // ---- phase B: neighbor lists, xsq partials, C2 softmax, q softmax ----
    for (int e = tid; e < S * DEG; e += BLOCK)
        neigh[e >> 4][e & 15] = dst[loc[e >> 4] * DEG + (e & 15)];
    for (int e = tid; e < S * 8; e += BLOCK) {
        int s0 = e >> 3, c = e & 7;
        const float4* xr = (const float4*)(x + (size_t)loc[s0] * D) + c * 4;
        float acc = 0.f;
        #pragma unroll
        for (int i = 0; i < 4; ++i) { float4 v = xr[i]; acc += v.x*v.x + v.y*v.y + v.z*v.z + v.w*v.w; }
        xsqp[s0][c] = acc;
    }
    // q = softmax(q0[t]) via DPP row reduction (all lanes)
    float vq = q0[t * MN + mc];
    float zq = act ? vq : NEG;
    float mq = rowmax16(zq);
    float sq = rowsum16(__expf(zq - mq));     // inactive: exp(NEG-mq)=0
    const float qm = __expf(vq - (mq + __logf(sq)));   // valid on act lanes
    // C2 = softmax(tmpl, axis=1): active lane m of quad 0 does column m
    if (act && q == 0) {
        float v[MN]; float cm = NEG;
        #pragma unroll
        for (int i = 0; i < MN; ++i) { v[i] = tmpl[t * MN * MN + i * MN + m]; cm = fmaxf(cm, v[i]); }
        float ssum = 0.f;
        #pragma unroll
        for (int i = 0; i < MN; ++i) { v[i] = __expf(v[i] - cm); ssum += v[i]; }
        float inv = 1.f / ssum;
        #pragma unroll
        for (int i = 0; i < MN; ++i) C2l[w][i][m] = v[i] * inv;
    }
    __syncthreads();

    // ---- phase C: adjacency -> bitmasks (atomicOr), xsq reduce ----
    for (int e = tid; e < S * S; e += BLOCK) {
        int a = e / S, b = e % S;
        int la = loc[a], lb = loc[b];
        bool adj = false;
        #pragma unroll
        for (int k = 0; k < DEG; ++k) adj = adj | (neigh[a][k] == lb) | (neigh[b][k] == la);
        if (a != b && adj) atomicOr(&C1m[a], 1u << b);
    }
    if (tid < S) {
        float acc = 0.f;
        #pragma unroll
        for (int c = 0; c < 8; ++c) acc += xsqp[tid][c];
        xsqs[tid] = acc;
    }
    __syncthreads();

    // ================= per-wave main (no more barriers) =================
    int sr[5];
    #pragma unroll
    for (int r = 0; r < 5; ++r) { int s0 = q + 4 * r; sr[r] = (s0 > 16) ? 16 : s0; }
    unsigned msk[5]; float npop[5];
    #pragma unroll
    for (int r = 0; r < 5; ++r) {
        msk[r]  = C1m[sr[r]];
        npop[r] = (float)__popc(msk[r]);
    }

    // M dots: x rows from global (L1/L2-resident)
    float dot[5] = {0,0,0,0,0};
    float sqf2 = 0.f;
    {
        const float4* f2p = (const float4*)(F2 + ((size_t)t * MN + mc) * D);
        const float4* xp0 = (const float4*)(x + (size_t)loc[sr[0]] * D);
        const float4* xp1 = (const float4*)(x + (size_t)loc[sr[1]] * D);
        const float4* xp2 = (const float4*)(x + (size_t)loc[sr[2]] * D);
        const float4* xp3 = (const float4*)(x + (size_t)loc[sr[3]] * D);
        const float4* xp4 = (const float4*)(x + (size_t)loc[sr[4]] * D);
        #pragma unroll 4
        for (int d4 = 0; d4 < D / 4; ++d4) {
            float4 f = f2p[d4];
            sqf2 += f.x*f.x + f.y*f.y + f.z*f.z + f.w*f.w;
            float4 v;
            v = xp0[d4]; dot[0] += f.x*v.x + f.y*v.y + f.z*v.z + f.w*v.w;
            v = xp1[d4]; dot[1] += f.x*v.x + f.y*v.y + f.z*v.z + f.w*v.w;
            v = xp2[d4]; dot[2] += f.x*v.x + f.y*v.y + f.z*v.z + f.w*v.w;
            v = xp3[d4]; dot[3] += f.x*v.x + f.y*v.y + f.z*v.z + f.w*v.w;
            v = xp4[d4]; dot[4] += f.x*v.x + f.y*v.y + f.z*v.z + f.w*v.w;
        }
    }

    // C2rot[i] = C2[mc][sigma^i(m)] — sigma probed with the same DPP op,
    // so the rotated-G dot product below is rotation-direction-proof.
    float C2rot[16];
    {
        int li = m;
        #pragma unroll
        for (int i = 0; i < 16; ++i) {
            C2rot[i] = (li < MN) ? C2l[w][mc][li] : 0.f;
            if (i < 15) li = dpp_movi(li);
        }
    }
    // hC2 = sum_j C2[mc][j]^2 q[j]; qC2m = sum_j C2[mc][j] q[j] (same pairing)
    float hC2 = 0.f, qC2m = 0.f;
    {
        float qrot = qm;
        #pragma unroll
        for (int i = 0; i < 16; ++i) {
            float cq = C2rot[i] * qrot;
            qC2m += cq;
            hC2  = fmaf(C2rot[i], cq, hC2);
            if (i < 15) qrot = dpp_movf<0x121>(qrot);
        }
    }

    const float alpha = 1.f / (1.f + __expf(-alpha0[0]));
    const float oma   = 1.f - alpha;
    const float p_    = 1.f / (float)S;
    const float fa4   = 40.f * alpha;         // logK = lkP + 40*alpha*tens
    const float qop   = qm * (float)S;        // q/p for folded v-update

    float lkP[5];
    #pragma unroll
    for (int r = 0; r < 5; ++r) {
        float M_ = xsqs[sr[r]] + sqf2 - 2.f * dot[r];
        float cC = npop[r] * (p_ * p_) * (float)S + hC2;  // hC1 = popc/S
        lkP[r] = -10.f * (oma * M_ + 2.f * alpha * cC);
    }

    // outer 0 analytic: G0 = p q^T => tens0[r] = p * qC2m * popc(msk[r])
    float tens[5], Kt[5], ub[5], v_, G[5];
    {
        float pq = p_ * qC2m;
        #pragma unroll
        for (int r = 0; r < 5; ++r) tens[r] = pq * npop[r];
    }

    for (int o = 1; o <= NOUT; ++o) {
        // K~ = exp(logK - rowmax) (rowmax via DPP)
        #pragma unroll
        for (int r = 0; r < 5; ++r) {
            float lk = fmaf(fa4, tens[r], lkP[r]);
            float rm = rowmax16(act ? lk : NEG);
            Kt[r] = act ? __expf(lk - rm) : 0.f;
        }
        // folded exp-domain Sinkhorn: û = rcp(K~ v); v = (Sq)*rcp(K~^T û)
        v_ = act ? 1.f : 0.f;
        #pragma unroll
        for (int it = 0; it < NSK; ++it) {
            #pragma unroll
            for (int r = 0; r < 5; ++r)
                ub[r] = fast_rcp(rowsum16(Kt[r] * v_));
            float cs = Kt[0]*ub[0] + Kt[1]*ub[1] + Kt[2]*ub[2] + Kt[3]*ub[3];
            cs += (q == 0) ? Kt[4]*ub[4] : 0.f;   // row 16 counted once
            cs += __shfl_xor(cs, 16, 64);
            cs += __shfl_xor(cs, 32, 64);
            v_ = act ? (qop * fast_rcp(cs)) : 0.f; // mask: rcp(0)=inf -> NaN
        }
        float pv = p_ * v_;
        #pragma unroll
        for (int r = 0; r < 5; ++r) G[r] = Kt[r] * ub[r] * pv;

        // H[own rows][m] = sum_k G[s][k]*C2[m][k] via DPP rotation (VALU-only)
        float H[5];
        #pragma unroll
        for (int r = 0; r < 5; ++r) {
            float h = 0.f, Gr = G[r];
            #pragma unroll
            for (int i = 0; i < 16; ++i) {
                h = fmaf(Gr, C2rot[i], h);
                if (i < 15) Gr = dpp_movf<0x121>(Gr);
            }
            H[r] = h;
        }
        // tens[s][m] = sum_{j in mask} H[j][m]
        #pragma unroll
        for (int r = 0; r < 5; ++r) tens[r] = 0.f;
        #pragma unroll
        for (int j = 0; j < 16; ++j) {
            float hj = __shfl(H[j >> 2], ((j & 3) << 4) + m, 64);
            #pragma unroll
            for (int r = 0; r < 5; ++r) tens[r] += ((msk[r] >> j) & 1u) ? hj : 0.f;
        }
        {
            float hj = H[4];   // row 16: replicated locally in every quad
            #pragma unroll
            for (int r = 0; r < 5; ++r) tens[r] += ((msk[r] >> 16) & 1u) ? hj : 0.f;
        }
    }

    // dist = sum G * (-0.1*lkP - a*cC - 2a*tens)
    float val = 0.f;
    #pragma unroll
    for (int r = 0; r < 5; ++r) {
        float cC = npop[r] * (p_ * p_) * (float)S + hC2;
        float integ = -0.1f * lkP[r] - alpha * cC - 2.f * alpha * tens[r];
        bool valid = act && (r < 4 || q == 0);
        val += valid ? G[r] * integ : 0.f;
    }
    val = rowsum16(val);
    val += __shfl_xor(val, 16, 64);
    val += __shfl_xor(val, 32, 64);
    if (lane == 0) out[n * T + t] = val;
}

extern "C" void kernel_launch(void* const* d_in, const int* in_sizes, int n_in,
                              void* d_out, int out_size, void* d_ws, size_t ws_size,
                              hipStream_t stream) {
    const float* x      = (const float*)d_in[0];
    const int*   edge   = (const int*)  d_in[1];
    const float* tmpl   = (const float*)d_in[2];
    const float* F2     = (const float*)d_in[3];
    const float* q0     = (const float*)d_in[4];
    const float* alpha0 = (const float*)d_in[5];
    float*       out    = (float*)d_out;

    hipLaunchKernelGGL(ltfgw_wave, dim3(NN * 5), dim3(BLOCK), 0, stream,
                       x, edge, tmpl, F2, q0, alpha0, out);
}

// Round 8
// 295.974 us; speedup vs baseline: 4.9545x; 1.5711x over previous
//
#include <hip/hip_runtime.h>
#include <math.h>

#define NN   5000
#define DEG  16
#define S    17
#define T    10
#define MN   10
#define D    128
#define NOUT 3
#define NSK  5

#define WPB   2            // waves per block = templates per block (main)
#define BLOCK (WPB * 64)
#define NEG   -3.0e38f

__device__ __forceinline__ float fast_rcp(float x) { return __builtin_amdgcn_rcpf(x); }

// DPP row_ror:k — pure-VALU cross-lane within each 16-lane row (~2cyc vs
// ds_bpermute's LDS-pipe ~35cyc latency).
template <int CTRL>
__device__ __forceinline__ float dpp_movf(float v) {
    return __int_as_float(__builtin_amdgcn_update_dpp(
        0, __float_as_int(v), CTRL, 0xF, 0xF, true));
}
__device__ __forceinline__ int dpp_movi(int v) {
    return __builtin_amdgcn_update_dpp(0, v, 0x121, 0xF, 0xF, true);
}
__device__ __forceinline__ float rowsum16(float v) {
    v += dpp_movf<0x121>(v);
    v += dpp_movf<0x122>(v);
    v += dpp_movf<0x124>(v);
    v += dpp_movf<0x128>(v);
    return v;
}
__device__ __forceinline__ float rowmax16(float v) {
    v = fmaxf(v, dpp_movf<0x121>(v));
    v = fmaxf(v, dpp_movf<0x122>(v));
    v = fmaxf(v, dpp_movf<0x124>(v));
    v = fmaxf(v, dpp_movf<0x128>(v));
    return v;
}

// ---------------- Pre-kernel: batch the per-node redundant work ----------------
// Round-8 rationale: round 7 was VALU-issue-bound (VALUBusy 86%). The M-dot
// phase (~1100 inst/lane, 2x lane waste) and adjacency setup (recomputed 5x
// per node) are batchable: Mp[n,c] = xsq[n] - 2*(x[n].F2f[c]) is a tiny
// global GEMM (64M MACs); masks[n][s] are per-node. Main kernel then just
// gathers 5 floats + 5 masks from L2-resident ws.
// Grid NN+1: block NN computes sqF2[100]; blocks n<NN do masks + Mp row.
__global__ __launch_bounds__(320) void ltfgw_pre(
    const float* __restrict__ x,        // [N, D]
    const int*   __restrict__ edge,     // [2, N*DEG]
    const float* __restrict__ F2,       // [T, MN, D] == [100, D] flat
    float*       __restrict__ wsMp,     // [N, 100]  xsq[n] - 2*dot
    unsigned*    __restrict__ wsMask,   // [N, 17]   adjacency bitmasks
    float*       __restrict__ wsSqF2)   // [100]
{
    const int n   = blockIdx.x;
    const int tid = threadIdx.x;
    const int* dst = edge + NN * DEG;

    if (n == NN) {                       // sqF2[c] = ||F2f[c]||^2
        if (tid < T * MN) {
            const float4* fr = (const float4*)(F2 + (size_t)tid * D);
            float acc = 0.f;
            #pragma unroll 8
            for (int i = 0; i < D / 4; ++i) {
                float4 f = fr[i];
                acc += f.x*f.x + f.y*f.y + f.z*f.z + f.w*f.w;
            }
            wsSqF2[tid] = acc;
        }
        return;
    }

    __shared__ int      loc[S];
    __shared__ int      neigh[S][DEG];
    __shared__ unsigned cm[S];
    __shared__ float    xsq_s;

    if (tid < S) { loc[tid] = (tid == 0) ? n : dst[n * DEG + tid - 1]; cm[tid] = 0u; }
    __syncthreads();

    if (tid < S * DEG) neigh[tid >> 4][tid & 15] = dst[loc[tid >> 4] * DEG + (tid & 15)];
    if (tid < 64) {                      // xsq[n] via wave-0 DPP reduce
        float v0 = x[(size_t)n * D + tid];
        float v1 = x[(size_t)n * D + 64 + tid];
        float pp = v0 * v0 + v1 * v1;
        pp = rowsum16(pp);
        pp += __shfl_xor(pp, 16, 64);
        pp += __shfl_xor(pp, 32, 64);
        if (tid == 0) xsq_s = pp;
    }
    __syncthreads();

    if (tid < S * S) {
        int a = tid / S, b = tid % S;
        int la = loc[a], lb = loc[b];
        bool adj = false;
        #pragma unroll
        for (int k = 0; k < DEG; ++k) adj = adj | (neigh[a][k] == lb) | (neigh[b][k] == la);
        if (a != b && adj) atomicOr(&cm[a], 1u << b);
    }
    __syncthreads();

    if (tid < S) wsMask[n * S + tid] = cm[tid];
    if (tid >= 32 && tid < 32 + T * MN) {  // Mp[n,c] = xsq - 2*(x[n].F2f[c])
        int c = tid - 32;
        const float4* fr = (const float4*)(F2 + (size_t)c * D);
        const float4* xr = (const float4*)(x + (size_t)n * D);
        float dotv = 0.f;
        #pragma unroll 8
        for (int d4 = 0; d4 < D / 4; ++d4) {
            float4 f = fr[d4], xv = xr[d4];
            dotv += f.x*xv.x + f.y*xv.y + f.z*xv.z + f.w*xv.w;
        }
        wsMp[n * (T * MN) + c] = xsq_s - 2.f * dotv;
    }
}

// ---------------- Main: one wave = one (node, template) OT problem ----------------
// Lane = q*16+m; lane owns rows s = q+4r (r=0..3) + row 16 (replicated
// across quads, counted once). All width-16 reductions via DPP. H = G*C2^T
// via DPP rotation (C2rot probed with the same DPP op -> direction-proof).
// outer-0 tens analytic (G0 = p q^T). Sinkhorn exp-domain with per-outer
// rowmax stabilization (exact vs reference log-domain; round-4 NaN lesson:
// v_ masked to 0 on inactive lanes). __launch_bounds__: block size ONLY
// (rounds 2-3: min-waves hint => allocator snaps + spills GBs).
__global__ __launch_bounds__(BLOCK) void ltfgw_wave(
    const int*      __restrict__ edge,     // [2, N*DEG]
    const float*    __restrict__ tmpl,     // [T, MN, MN]
    const float*    __restrict__ q0,       // [T, MN]
    const float*    __restrict__ alpha0,   // [1]
    const float*    __restrict__ wsMp,     // [N, 100]
    const unsigned* __restrict__ wsMask,   // [N, 17]
    const float*    __restrict__ wsSqF2,   // [100]
    float*          __restrict__ out)      // [N, T]
{
    const int blk  = blockIdx.x;
    const int n    = blk / 5;
    const int tp   = blk % 5;
    const int tid  = threadIdx.x;
    const int w    = tid >> 6;
    const int t    = tp * 2 + w;
    const int lane = tid & 63;
    const int q    = lane >> 4;
    const int m    = lane & 15;
    const bool act = (m < MN);
    const int mc   = act ? m : (MN - 1);

    __shared__ float C2l[WPB][MN][17];     // stride 17: conflict-free

    const int* dst = edge + NN * DEG;

    // q = softmax(q0[t]) via DPP row reduction (all lanes)
    float vq = q0[t * MN + mc];
    float zq = act ? vq : NEG;
    float mq = rowmax16(zq);
    float sq = rowsum16(__expf(zq - mq));     // inactive: exp(NEG-mq)=0
    const float qm = __expf(vq - (mq + __logf(sq)));   // valid on act lanes
    // C2 = softmax(tmpl, axis=1): active lane m of quad 0 does column m
    if (act && q == 0) {
        float v[MN]; float cm = NEG;
        #pragma unroll
        for (int i = 0; i < MN; ++i) { v[i] = tmpl[t * MN * MN + i * MN + m]; cm = fmaxf(cm, v[i]); }
        float ssum = 0.f;
        #pragma unroll
        for (int i = 0; i < MN; ++i) { v[i] = __expf(v[i] - cm); ssum += v[i]; }
        float inv = 1.f / ssum;
        #pragma unroll
        for (int i = 0; i < MN; ++i) C2l[w][i][m] = v[i] * inv;
    }

    // per-row gathers (L1/L2-resident ws): rows sr[r] = q+4r, clamp 16
    int sr[5];
    #pragma unroll
    for (int r = 0; r < 5; ++r) { int s0 = q + 4 * r; sr[r] = (s0 > 16) ? 16 : s0; }
    unsigned msk[5]; float npop[5]; float Mp[5];
    const int cidx = t * MN + mc;
    #pragma unroll
    for (int r = 0; r < 5; ++r) {
        int lr  = (sr[r] == 0) ? n : dst[n * DEG + sr[r] - 1];
        msk[r]  = wsMask[n * S + sr[r]];
        npop[r] = (float)__popc(msk[r]);
        Mp[r]   = wsMp[lr * (T * MN) + cidx];
    }
    const float sqf2c = wsSqF2[cidx];

    __syncthreads();   // C2l ready

    // C2rot[i] = C2[mc][sigma^i(m)] — sigma probed with the same DPP op,
    // so the rotated-G dot product below is rotation-direction-proof.
    float C2rot[16];
    {
        int li = m;
        #pragma unroll
        for (int i = 0; i < 16; ++i) {
            C2rot[i] = (li < MN) ? C2l[w][mc][li] : 0.f;
            if (i < 15) li = dpp_movi(li);
        }
    }
    // hC2 = sum_j C2[mc][j]^2 q[j]; qC2m = sum_j C2[mc][j] q[j]
    float hC2 = 0.f, qC2m = 0.f;
    {
        float qrot = qm;
        #pragma unroll
        for (int i = 0; i < 16; ++i) {
            float cq = C2rot[i] * qrot;
            qC2m += cq;
            hC2  = fmaf(C2rot[i], cq, hC2);
            if (i < 15) qrot = dpp_movf<0x121>(qrot);
        }
    }

    const float alpha = 1.f / (1.f + __expf(-alpha0[0]));
    const float oma   = 1.f - alpha;
    const float p_    = 1.f / (float)S;
    const float fa4   = 40.f * alpha;         // logK = lkP + 40*alpha*tens
    const float qop   = qm * (float)S;        // q/p for folded v-update

    float lkP[5];
    #pragma unroll
    for (int r = 0; r < 5; ++r) {
        float M_ = Mp[r] + sqf2c;             // xsq + sqf2 - 2*dot
        float cC = npop[r] * p_ + hC2;        // hC1 = popc/S
        lkP[r] = -10.f * (oma * M_ + 2.f * alpha * cC);
    }

    // outer 0 analytic: G0 = p q^T => tens0[r] = p * qC2m * popc(msk[r])
    float tens[5], Kt[5], ub[5], v_, G[5];
    {
        float pq = p_ * qC2m;
        #pragma unroll
        for (int r = 0; r < 5; ++r) tens[r] = pq * npop[r];
    }

    for (int o = 1; o <= NOUT; ++o) {
        // K~ = exp(logK - rowmax) (rowmax via DPP)
        #pragma unroll
        for (int r = 0; r < 5; ++r) {
            float lk = fmaf(fa4, tens[r], lkP[r]);
            float rm = rowmax16(act ? lk : NEG);
            Kt[r] = act ? __expf(lk - rm) : 0.f;
        }
        // folded exp-domain Sinkhorn: û = rcp(K~ v); v = (Sq)*rcp(K~^T û)
        v_ = act ? 1.f : 0.f;
        #pragma unroll
        for (int it = 0; it < NSK; ++it) {
            #pragma unroll
            for (int r = 0; r < 5; ++r)
                ub[r] = fast_rcp(rowsum16(Kt[r] * v_));
            float cs = Kt[0]*ub[0] + Kt[1]*ub[1] + Kt[2]*ub[2] + Kt[3]*ub[3];
            cs += (q == 0) ? Kt[4]*ub[4] : 0.f;   // row 16 counted once
            cs += __shfl_xor(cs, 16, 64);
            cs += __shfl_xor(cs, 32, 64);
            v_ = act ? (qop * fast_rcp(cs)) : 0.f; // mask: rcp(0)=inf -> NaN
        }
        float pv = p_ * v_;
        #pragma unroll
        for (int r = 0; r < 5; ++r) G[r] = Kt[r] * ub[r] * pv;

        // H[own rows][m] = sum_k G[s][k]*C2[m][k] via DPP rotation (VALU-only)
        float H[5];
        #pragma unroll
        for (int r = 0; r < 5; ++r) {
            float h = 0.f, Gr = G[r];
            #pragma unroll
            for (int i = 0; i < 16; ++i) {
                h = fmaf(Gr, C2rot[i], h);
                if (i < 15) Gr = dpp_movf<0x121>(Gr);
            }
            H[r] = h;
        }
        // tens[s][m] = sum_{j in mask} H[j][m]
        #pragma unroll
        for (int r = 0; r < 5; ++r) tens[r] = 0.f;
        #pragma unroll
        for (int j = 0; j < 16; ++j) {
            float hj = __shfl(H[j >> 2], ((j & 3) << 4) + m, 64);
            #pragma unroll
            for (int r = 0; r < 5; ++r) tens[r] += ((msk[r] >> j) & 1u) ? hj : 0.f;
        }
        {
            float hj = H[4];   // row 16: replicated locally in every quad
            #pragma unroll
            for (int r = 0; r < 5; ++r) tens[r] += ((msk[r] >> 16) & 1u) ? hj : 0.f;
        }
    }

    // dist = sum G * (-0.1*lkP - a*cC - 2a*tens)
    float val = 0.f;
    #pragma unroll
    for (int r = 0; r < 5; ++r) {
        float cC = npop[r] * p_ + hC2;
        float integ = -0.1f * lkP[r] - alpha * cC - 2.f * alpha * tens[r];
        bool valid = act && (r < 4 || q == 0);
        val += valid ? G[r] * integ : 0.f;
    }
    val = rowsum16(val);
    val += __shfl_xor(val, 16, 64);
    val += __shfl_xor(val, 32, 64);
    if (lane == 0) out[n * T + t] = val;
}

extern "C" void kernel_launch(void* const* d_in, const int* in_sizes, int n_in,
                              void* d_out, int out_size, void* d_ws, size_t ws_size,
                              hipStream_t stream) {
    const float* x      = (const float*)d_in[0];
    const int*   edge   = (const int*)  d_in[1];
    const float* tmpl   = (const float*)d_in[2];
    const float* F2     = (const float*)d_in[3];
    const float* q0     = (const float*)d_in[4];
    const float* alpha0 = (const float*)d_in[5];
    float*       out    = (float*)d_out;

    // ws layout: Mp [N*100] f32 | masks [N*17] u32 | sqF2 [100] f32  (~2.34 MB)
    float*    wsMp    = (float*)d_ws;
    unsigned* wsMask  = (unsigned*)((char*)d_ws + (size_t)NN * T * MN * 4);
    float*    wsSqF2  = (float*)((char*)d_ws + (size_t)NN * T * MN * 4 + (size_t)NN * S * 4);

    hipLaunchKernelGGL(ltfgw_pre, dim3(NN + 1), dim3(320), 0, stream,
                       x, edge, F2, wsMp, wsMask, wsSqF2);
    hipLaunchKernelGGL(ltfgw_wave, dim3(NN * 5), dim3(BLOCK), 0, stream,
                       edge, tmpl, q0, alpha0, wsMp, wsMask, wsSqF2, out);
}